// Round 3
// baseline (175.341 us; speedup 1.0000x reference)
//
#include <hip/hip_runtime.h>
#include <cstdint>

typedef short  s16x8 __attribute__((ext_vector_type(8)));
typedef float  f32x4 __attribute__((ext_vector_type(4)));
typedef int    i32x4 __attribute__((ext_vector_type(4)));
typedef unsigned short u16x4 __attribute__((ext_vector_type(4)));

#define OUT_F 11008
#define IN_F  4096
#define MROWS 512
#define GQ    704512   // int32 elements per W_q row
#define HALF  5504     // 32*172: o and o+HALF share a packed byte
#define RMOD  172

__device__ __forceinline__ unsigned short f2bf(float f) {
  unsigned u = __builtin_bit_cast(unsigned, f);
  return (unsigned short)((u + 0x8000u) >> 16);   // round-half-up to bf16
}

// ---------------- prelude 1: f32 -> bf16 for x and U ----------------
__global__ __launch_bounds__(256) void convert_k(const float* __restrict__ x,
                                                 const float* __restrict__ U,
                                                 unsigned short* __restrict__ xbf,
                                                 unsigned short* __restrict__ Ubf) {
  int i = blockIdx.x * 256 + threadIdx.x;
  const int NX = (MROWS * IN_F) / 4;   // 524288
  const int NU = (OUT_F * 32) / 4;     // 88064
  const float* src; unsigned short* dst; int idx;
  if (i < NX) { src = x; dst = xbf; idx = i; }
  else        { idx = i - NX; if (idx >= NU) return; src = U; dst = Ubf; }
  f32x4 v = *(const f32x4*)(src + (size_t)idx * 4);
  u16x4 o;
  o[0] = f2bf(v[0]); o[1] = f2bf(v[1]); o[2] = f2bf(v[2]); o[3] = f2bf(v[3]);
  *(u16x4*)(dst + (size_t)idx * 4) = o;
}

// ---------------- prelude 2: P = x @ V^T (512x32), split-K atomics ----------------
__global__ __launch_bounds__(256) void pcalc_k(const float* __restrict__ x,
                                               const float* __restrict__ V,
                                               float* __restrict__ P) {
  int m  = (blockIdx.x >> 3) * 8 + (threadIdx.x >> 5);   // 0..511
  int j  = threadIdx.x & 31;                             // 0..31
  int k0 = (blockIdx.x & 7) * 512;
  const float* xr = x + (size_t)m * IN_F + k0;
  const float* vr = V + (size_t)j * IN_F + k0;
  float a = 0.f;
#pragma unroll 4
  for (int k = 0; k < 512; k += 4) {
    f32x4 xv = *(const f32x4*)(xr + k);
    f32x4 vv = *(const f32x4*)(vr + k);
    a += xv[0]*vv[0] + xv[1]*vv[1] + xv[2]*vv[2] + xv[3]*vv[3];
  }
  atomicAdd(P + m * 32 + j, a);
}

// ---------------- main fused dequant GEMM ----------------
// C[512][11008] = xbf @ W^T + bias + P @ Ubf^T
// Block tile: 128 m x 128 o (paired: 64 rows o0+tr and 64 rows o0+HALF+tr).
// LDS: A dbuf at smem+{0,8192}, B dbuf at smem+16384+{0,8192} (shorts).
__global__ __launch_bounds__(256, 2) void milo_gemm(
    const unsigned short* __restrict__ xbf,
    const int*            __restrict__ Wq,
    const float*          __restrict__ scale,
    const float*          __restrict__ zero,
    const float*          __restrict__ Pf,
    const unsigned short* __restrict__ Ubf,
    const float*          __restrict__ bias,
    float*                __restrict__ out)
{
  extern __shared__ __align__(16) unsigned short smem[];

  const int tid  = threadIdx.x;
  const int lane = tid & 63;
  const int wid  = tid >> 6;   // 0..3
  const int wm   = wid >> 1;   // wave row (0..1): m sub-tile 64
  const int wn   = wid & 1;    // wave col (0..1): o sub-tile 64

  // XCD-aware swizzle: 344 = 8 * 43 (bijective)
  int raw = blockIdx.x;
  int bid = (raw & 7) * 43 + (raw >> 3);
  int gn  = bid >> 2;          // 0..85
  int gm  = bid & 3;           // 0..3
  const int m0 = gm * 128;
  const int o0 = gn * 64;

  // ---- W staging precompute: thread -> (4 rows) x (4-col chunk) ----
  const int c4 = (tid & 15) * 4;
  unsigned wq_off[4], sc_off[4];
#pragma unroll
  for (int p = 0; p < 4; ++p) {
    int tr = (tid >> 4) + p * 16;          // 0..63 (low-half row)
    int o  = o0 + tr;                      // < 5504 -> g in [0,32)
    int g  = o / RMOD;
    int r  = o - g * RMOD;
    wq_off[p] = (unsigned)g * (unsigned)GQ + (unsigned)r * (unsigned)IN_F + c4;
    sc_off[p] = (unsigned)r * (unsigned)IN_F + c4;
  }
  // ---- A staging (global_load_lds) source offsets, linear LDS dest ----
  unsigned a_src[4];
#pragma unroll
  for (int it = 0; it < 4; ++it)
    a_src[it] = (unsigned)(m0 + it * 32 + wid * 8 + (lane >> 3)) * IN_F + (lane & 7) * 8;

  // ---- fragment LDS offsets ----
  const int a_base = (wm * 64 + (lane & 15)) * 64 + ((lane >> 4) * 8);
  const int b_base = (wn * 64 + (lane & 15)) * 64 + ((lane >> 4) * 8);

  f32x4 acc[4][4];
  {
    f32x4 zf = {0.f, 0.f, 0.f, 0.f};
#pragma unroll
    for (int i = 0; i < 4; ++i)
#pragma unroll
      for (int j = 0; j < 4; ++j) acc[i][j] = zf;
  }

  i32x4 wq[4]; f32x4 sc[4], zr[4];
  f32x4 pf[4]; i32x4 uu[2];

  auto issueA = [&](int buf, int k0) {
    unsigned short* Adst = smem + buf * 8192;
#pragma unroll
    for (int it = 0; it < 4; ++it) {
      __builtin_amdgcn_global_load_lds(
          (const __attribute__((address_space(1))) unsigned int*)(xbf + a_src[it] + k0),
          (__attribute__((address_space(3))) unsigned int*)(Adst + (it * 32 + wid * 8) * 64),
          16, 0, 0);
    }
  };
  auto loadB = [&](int k0) {
#pragma unroll
    for (int p = 0; p < 4; ++p) {
      wq[p] = *(const i32x4*)(Wq + wq_off[p] + k0);
      sc[p] = *(const f32x4*)(scale + sc_off[p] + k0);
      zr[p] = *(const f32x4*)(zero + sc_off[p] + k0);
    }
  };
  auto writeB = [&](int buf) {
    unsigned short* Bn = smem + 16384 + buf * 8192;
#pragma unroll
    for (int p = 0; p < 4; ++p) {
      int tr = (tid >> 4) + p * 16;
      u16x4 h4, l4;
#pragma unroll
      for (int e = 0; e < 4; ++e) {
        int v = wq[p][e];
        float s = sc[p][e], z = zr[p][e];
        h4[e] = f2bf(((float)((v >> 4) & 0xF) - z) * s);
        l4[e] = f2bf(((float)(v & 0xF) - z) * s);
      }
      *(u16x4*)(Bn + tr * 64 + c4)        = h4;   // hi nibble -> g<32  -> o0+tr
      *(u16x4*)(Bn + (tr + 64) * 64 + c4) = l4;   // lo nibble -> g>=32 -> o0+HALF+tr
    }
  };
  auto loadF = [&]() {
    int rw = tid >> 1, h = tid & 1;
#pragma unroll
    for (int q = 0; q < 4; ++q)
      pf[q] = *(const f32x4*)(Pf + (m0 + rw) * 32 + h * 16 + q * 4);
    int oc = (rw < 64) ? (o0 + rw) : (HALF + o0 + rw - 64);
#pragma unroll
    for (int q = 0; q < 2; ++q)
      uu[q] = *(const i32x4*)(Ubf + (size_t)oc * 32 + h * 16 + q * 8);
  };
  auto writeF = [&](int buf) {
    unsigned short* An = smem + buf * 8192;
    unsigned short* Bn = smem + 16384 + buf * 8192;
    int rw = tid >> 1, h = tid & 1;
    i32x4 zi = {0, 0, 0, 0};
#pragma unroll
    for (int q = 0; q < 4; ++q) {
      u16x4 t4;
      t4[0] = f2bf(pf[q][0]); t4[1] = f2bf(pf[q][1]);
      t4[2] = f2bf(pf[q][2]); t4[3] = f2bf(pf[q][3]);
      *(u16x4*)(An + rw * 64 + h * 16 + q * 4) = t4;
    }
    // zero-pad k 32..63 COMPLETELY: each of the 2 threads/row zeroes its
    // 16-short half (two aligned 16B writes).
    int zbase = rw * 64 + 32 + h * 16;
    *(i32x4*)(An + zbase)     = zi;
    *(i32x4*)(An + zbase + 8) = zi;
#pragma unroll
    for (int q = 0; q < 2; ++q)
      *(i32x4*)(Bn + rw * 64 + h * 16 + q * 8) = uu[q];
    *(i32x4*)(Bn + zbase)     = zi;
    *(i32x4*)(Bn + zbase + 8) = zi;
  };
  auto compute = [&](int buf) {
    const unsigned short* Ac = smem + buf * 8192;
    const unsigned short* Bc = smem + 16384 + buf * 8192;
#pragma unroll
    for (int kk = 0; kk < 64; kk += 32) {
      s16x8 av[4], bv[4];
#pragma unroll
      for (int f = 0; f < 4; ++f) av[f] = *(const s16x8*)(Ac + a_base + f * 1024 + kk);
#pragma unroll
      for (int f = 0; f < 4; ++f) bv[f] = *(const s16x8*)(Bc + b_base + f * 1024 + kk);
#pragma unroll
      for (int i = 0; i < 4; ++i)
#pragma unroll
        for (int j = 0; j < 4; ++j)
          acc[i][j] = __builtin_amdgcn_mfma_f32_16x16x32_bf16(av[i], bv[j], acc[i][j], 0, 0, 0);
    }
  };

  // ---- prologue: stage tile 0 ----
  loadB(0);
  issueA(0, 0);
  writeB(0);
  __syncthreads();

  // ---- main K loop: 64 steps of BK=64 ----
  for (int t = 0; t < 63; ++t) {
    int cur = t & 1, nxt = cur ^ 1;
    loadB((t + 1) * 64);
    issueA(nxt, (t + 1) * 64);
    compute(cur);
    writeB(nxt);
    __syncthreads();
  }
  // ---- t=63: compute last W tile, stage low-rank tile (P,U) ----
  loadF();
  compute(1);
  writeF(0);
  __syncthreads();
  // ---- t=64: low-rank correction K-step ----
  compute(0);

  // ---- epilogue: bias + store ----
#pragma unroll
  for (int fn = 0; fn < 4; ++fn) {
    int c = wn * 64 + fn * 16 + (lane & 15);
    int o = (c < 64) ? (o0 + c) : (HALF + o0 + (c - 64));
    float bv = bias[o];
#pragma unroll
    for (int fm = 0; fm < 4; ++fm) {
      int m = m0 + wm * 64 + fm * 16 + ((lane >> 4) << 2);
#pragma unroll
      for (int j = 0; j < 4; ++j)
        out[(size_t)(m + j) * OUT_F + o] = acc[fm][fn][j] + bv;
    }
  }
}

extern "C" void kernel_launch(void* const* d_in, const int* in_sizes, int n_in,
                              void* d_out, int out_size, void* d_ws, size_t ws_size,
                              hipStream_t stream) {
  const float* x     = (const float*)d_in[0];
  const int*   Wq    = (const int*)d_in[1];
  const float* scale = (const float*)d_in[2];
  const float* zero  = (const float*)d_in[3];
  const float* U     = (const float*)d_in[4];
  const float* V     = (const float*)d_in[5];
  const float* bias  = (const float*)d_in[6];
  float* out = (float*)d_out;

  unsigned short* xbf = (unsigned short*)d_ws;                 // 512*4096 bf16
  unsigned short* Ubf = xbf + (size_t)MROWS * IN_F;            // 11008*32 bf16
  float*          P   = (float*)(Ubf + (size_t)OUT_F * 32);    // 512*32 f32

  (void)hipMemsetAsync(P, 0, (size_t)MROWS * 32 * sizeof(float), stream);
  convert_k<<<2392, 256, 0, stream>>>(x, U, xbf, Ubf);
  pcalc_k<<<512, 256, 0, stream>>>(x, V, P);
  milo_gemm<<<344, 256, 65536, stream>>>(xbf, Wq, scale, zero, P, Ubf, bias, out);
}